// Round 6
// baseline (614.198 us; speedup 1.0000x reference)
//
#include <hip/hip_runtime.h>

#define NTOT 16384
#define NBAG 64
#define NMC  4

typedef __attribute__((ext_vector_type(8))) short bf8_t;       // 8 x bf16 payload
typedef __attribute__((ext_vector_type(4))) float f32x4;
typedef __attribute__((ext_vector_type(8))) unsigned short u16x8;

#define GLD16(g, l) __builtin_amdgcn_global_load_lds( \
    (const __attribute__((address_space(1))) void*)(g), \
    (__attribute__((address_space(3))) void*)(l), 16, 0, 0)

static __device__ __forceinline__ unsigned short f2bf(float x){
  unsigned int u = __float_as_uint(x);
  u += 0x7fffu + ((u >> 16) & 1u);
  return (unsigned short)(u >> 16);
}
static __device__ __forceinline__ float bf2f(unsigned short h){
  return __uint_as_float(((unsigned int)h) << 16);
}
static __device__ __forceinline__ f32x4 mfma16(bf8_t a, bf8_t b, f32x4 c){
  return __builtin_amdgcn_mfma_f32_16x16x32_bf16(a, b, c, 0, 0, 0);
}

// ---------- conversion / repack kernels ----------
__global__ __launch_bounds__(256) void k_cvt(const float* __restrict__ src,
    unsigned short* __restrict__ dst, int n8){
  for (int i = blockIdx.x*256 + threadIdx.x; i < n8; i += gridDim.x*256){
    float4 v0 = ((const float4*)src)[i*2];
    float4 v1 = ((const float4*)src)[i*2+1];
    u16x8 o;
    o[0]=f2bf(v0.x); o[1]=f2bf(v0.y); o[2]=f2bf(v0.z); o[3]=f2bf(v0.w);
    o[4]=f2bf(v1.x); o[5]=f2bf(v1.y); o[6]=f2bf(v1.z); o[7]=f2bf(v1.w);
    ((u16x8*)dst)[i] = o;
  }
}

// dst[kg][c][i] = bf16(src[(8kg+i)*N + c]);  batched over blockIdx.y
__global__ __launch_bounds__(256) void k_pack8(const float* __restrict__ src,
    unsigned short* __restrict__ dst, int K, int N){
  const size_t base = (size_t)blockIdx.y * K * N;
  int idx = blockIdx.x*256 + threadIdx.x;     // idx = kg*N + c
  int kg = idx / N, c = idx % N;
  const float* s = src + base + (size_t)(kg*8)*N + c;
  u16x8 o;
  #pragma unroll
  for (int i=0;i<8;i++) o[i] = f2bf(s[(size_t)i*N]);
  ((u16x8*)(dst + base))[idx] = o;
}

// ---------- rf-features + LayerNorm epilogue (RT=4 rowtiles, 4 col-groups) ----------
// acc[rt][ct][j] = z for row (n0 + rowg*64 + rt*16 + 4g + j), col (colg*128 + ct*16 + li)
// sum(f^2) over 1024 features = 1 exactly (cos^2+sin^2), so var = 1/1024 - mu^2.
static __device__ __forceinline__ void rf_ln_store4(f32x4 (&acc)[4][8],
    unsigned short* __restrict__ phiM, float* rowp, int rowg,
    int n0, int colg, int l){
  const float scale = 0.044194173824159216f;  // 1/sqrt(512)
  const int g = l >> 4, li = l & 15;
  const int row0 = rowg*64;
  float part[4][4];
  #pragma unroll
  for (int rt=0; rt<4; rt++){
    #pragma unroll
    for (int j=0;j<4;j++){
      float s = 0.f;
      #pragma unroll
      for (int ct=0; ct<8; ct++){
        float sn, cs; __sincosf(acc[rt][ct][j], &sn, &cs);
        s += sn + cs;
      }
      #pragma unroll
      for (int off=1; off<16; off<<=1) s += __shfl_xor(s, off);
      part[rt][j] = s;
    }
  }
  if (li == 0){
    #pragma unroll
    for (int rt=0; rt<4; rt++)
      #pragma unroll
      for (int j=0;j<4;j++)
        rowp[(row0 + rt*16 + 4*g + j)*4 + colg] = part[rt][j];
  }
  __syncthreads();
  #pragma unroll
  for (int rt=0; rt<4; rt++){
    #pragma unroll
    for (int j=0;j<4;j++){
      int rb = row0 + rt*16 + 4*g + j;
      float tot = rowp[rb*4+0] + rowp[rb*4+1] + rowp[rb*4+2] + rowp[rb*4+3];
      float mu = tot * (scale / 1024.0f);
      float rs = 1.0f / sqrtf((1.0f/1024.0f) - mu*mu + 1e-5f);
      size_t base = (size_t)(n0 + rb) * 1024;
      #pragma unroll
      for (int ct=0; ct<8; ct++){
        int c = colg*128 + ct*16 + li;
        float sn, cs; __sincosf(acc[rt][ct][j], &sn, &cs);
        phiM[base + c]       = f2bf((cs*scale - mu)*rs);
        phiM[base + 512 + c] = f2bf((sn*scale - mu)*rs);
      }
    }
  }
}

// ================= depth-2 pipelined GEMM kernels =================
// 512 thr (8 waves = 2 rowg x 4 colg); wave tile 64 rows x 128 cols (RT=4, CT=8).
// 4-buffer ring, counted vmcnt(16) = 2 iters x 8 vmem ops in flight, 1 barrier/iter.
// Each B-fragment feeds 4 MFMAs -> block LDS reads halved vs 4-rowg layout.

// ---------- K1: z1 = Xb @ Om1f[m] -> rf/LN -> phi ----------
__global__ __launch_bounds__(512,2) void k_phi1(const unsigned short* __restrict__ Xb,
    const unsigned short* __restrict__ Om1f, unsigned short* __restrict__ phi){
  const int m = blockIdx.y, n0 = blockIdx.x*128;
  const int t = threadIdx.x, w = t>>6, l = t&63;
  const int g = l>>4, li = l&15;
  const int rowg = w & 1, colg = w >> 1;
  const int wvb = t & ~63;
  __shared__ unsigned short Bs[4][16384];   // 4 x 32KB ring
  __shared__ float rowp[512];               // 128 rows x 4 colg
  f32x4 acc[4][8];
  const f32x4 z4 = {0.f,0.f,0.f,0.f};
  #pragma unroll
  for (int rt=0;rt<4;rt++)
    #pragma unroll
    for (int ct=0;ct<8;ct++) acc[rt][ct] = z4;
  const unsigned short* bsrc = Om1f + (size_t)m*524288;
  const unsigned short* abase = Xb + (size_t)(n0 + rowg*64 + li)*1024 + g*8;
  bf8_t a_c[4], a_n[4];
  #pragma unroll
  for (int it=0; it<4; it++) GLD16(bsrc + it*4096 + t*8, &Bs[0][0] + it*4096 + wvb*8);
  #pragma unroll
  for (int rt=0; rt<4; rt++) a_c[rt] = *(const bf8_t*)(abase + rt*16384);
  #pragma unroll
  for (int it=0; it<4; it++) GLD16(bsrc + 16384 + it*4096 + t*8, &Bs[1][0] + it*4096 + wvb*8);
  #pragma unroll
  for (int rt=0; rt<4; rt++) a_n[rt] = *(const bf8_t*)(abase + rt*16384 + 32);
  for (int ks=0; ks<32; ks++){
    int ksn = ks+2 < 32 ? ks+2 : 31;
    const unsigned short* sb = bsrc + (size_t)ksn*16384;
    unsigned short* db = &Bs[(ks+2)&3][0];
    #pragma unroll
    for (int it=0; it<4; it++) GLD16(sb + it*4096 + t*8, db + it*4096 + wvb*8);
    bf8_t a_nn[4];
    #pragma unroll
    for (int rt=0; rt<4; rt++) a_nn[rt] = *(const bf8_t*)(abase + rt*16384 + ksn*32);
    asm volatile("s_waitcnt vmcnt(16)" ::: "memory");
    __builtin_amdgcn_sched_barrier(0);
    __builtin_amdgcn_s_barrier();
    __builtin_amdgcn_sched_barrier(0);
    const unsigned short* bb = &Bs[ks&3][0] + g*4096 + (colg*128 + li)*8;
    __builtin_amdgcn_s_setprio(1);
    #pragma unroll
    for (int ct=0; ct<8; ct++){
      bf8_t b = *(const bf8_t*)(bb + ct*128);
      #pragma unroll
      for (int rt=0; rt<4; rt++) acc[rt][ct] = mfma16(a_c[rt], b, acc[rt][ct]);
    }
    __builtin_amdgcn_s_setprio(0);
    #pragma unroll
    for (int rt=0; rt<4; rt++){ a_c[rt]=a_n[rt]; a_n[rt]=a_nn[rt]; }
  }
  rf_ln_store4(acc, phi + (size_t)m*NTOT*1024, rowp, rowg, n0, colg, l);
}

// ---------- K2a: h = phi @ W1f + b1 -> bf16 ----------
__global__ __launch_bounds__(512,2) void k_phi2a(const unsigned short* __restrict__ phi,
    const unsigned short* __restrict__ W1f, const float* __restrict__ b1,
    unsigned short* __restrict__ h){
  const int m = blockIdx.y, n0 = blockIdx.x*128;
  const int t = threadIdx.x, w = t>>6, l = t&63;
  const int g = l>>4, li = l&15;
  const int rowg = w & 1, colg = w >> 1;
  const int wvb = t & ~63;
  __shared__ unsigned short Bs[4][16384];
  f32x4 acc[4][8];
  const f32x4 z4 = {0.f,0.f,0.f,0.f};
  #pragma unroll
  for (int rt=0;rt<4;rt++)
    #pragma unroll
    for (int ct=0;ct<8;ct++) acc[rt][ct] = z4;
  const unsigned short* abase = phi + ((size_t)m*NTOT + n0 + rowg*64 + li)*1024 + g*8;
  bf8_t a_c[4], a_n[4];
  #pragma unroll
  for (int it=0; it<4; it++) GLD16(W1f + it*4096 + t*8, &Bs[0][0] + it*4096 + wvb*8);
  #pragma unroll
  for (int rt=0; rt<4; rt++) a_c[rt] = *(const bf8_t*)(abase + rt*16384);
  #pragma unroll
  for (int it=0; it<4; it++) GLD16(W1f + 16384 + it*4096 + t*8, &Bs[1][0] + it*4096 + wvb*8);
  #pragma unroll
  for (int rt=0; rt<4; rt++) a_n[rt] = *(const bf8_t*)(abase + rt*16384 + 32);
  for (int ks=0; ks<32; ks++){
    int ksn = ks+2 < 32 ? ks+2 : 31;
    const unsigned short* sb = W1f + (size_t)ksn*16384;
    unsigned short* db = &Bs[(ks+2)&3][0];
    #pragma unroll
    for (int it=0; it<4; it++) GLD16(sb + it*4096 + t*8, db + it*4096 + wvb*8);
    bf8_t a_nn[4];
    #pragma unroll
    for (int rt=0; rt<4; rt++) a_nn[rt] = *(const bf8_t*)(abase + rt*16384 + ksn*32);
    asm volatile("s_waitcnt vmcnt(16)" ::: "memory");
    __builtin_amdgcn_sched_barrier(0);
    __builtin_amdgcn_s_barrier();
    __builtin_amdgcn_sched_barrier(0);
    const unsigned short* bb = &Bs[ks&3][0] + g*4096 + (colg*128 + li)*8;
    __builtin_amdgcn_s_setprio(1);
    #pragma unroll
    for (int ct=0; ct<8; ct++){
      bf8_t b = *(const bf8_t*)(bb + ct*128);
      #pragma unroll
      for (int rt=0; rt<4; rt++) acc[rt][ct] = mfma16(a_c[rt], b, acc[rt][ct]);
    }
    __builtin_amdgcn_s_setprio(0);
    #pragma unroll
    for (int rt=0; rt<4; rt++){ a_c[rt]=a_n[rt]; a_n[rt]=a_nn[rt]; }
  }
  #pragma unroll
  for (int rt=0; rt<4; rt++){
    #pragma unroll
    for (int ct=0; ct<8; ct++){
      int c = colg*128 + ct*16 + li;
      float bv = b1[c];
      #pragma unroll
      for (int j=0;j<4;j++)
        h[((size_t)m*NTOT + n0 + rowg*64 + rt*16 + 4*g + j)*512 + c] = f2bf(acc[rt][ct][j] + bv);
    }
  }
}

// ---------- K2b: z2 = h @ Om2f[m] -> rf/LN -> phi (in place) ----------
__global__ __launch_bounds__(512,2) void k_phi2b(const unsigned short* __restrict__ h,
    const unsigned short* __restrict__ Om2f, unsigned short* __restrict__ phi){
  const int m = blockIdx.y, n0 = blockIdx.x*128;
  const int t = threadIdx.x, w = t>>6, l = t&63;
  const int g = l>>4, li = l&15;
  const int rowg = w & 1, colg = w >> 1;
  const int wvb = t & ~63;
  __shared__ unsigned short Bs[4][16384];
  __shared__ float rowp[512];
  f32x4 acc[4][8];
  const f32x4 z4 = {0.f,0.f,0.f,0.f};
  #pragma unroll
  for (int rt=0;rt<4;rt++)
    #pragma unroll
    for (int ct=0;ct<8;ct++) acc[rt][ct] = z4;
  const unsigned short* bsrc = Om2f + (size_t)m*262144;
  const unsigned short* abase = h + ((size_t)m*NTOT + n0 + rowg*64 + li)*512 + g*8;
  bf8_t a_c[4], a_n[4];
  #pragma unroll
  for (int it=0; it<4; it++) GLD16(bsrc + it*4096 + t*8, &Bs[0][0] + it*4096 + wvb*8);
  #pragma unroll
  for (int rt=0; rt<4; rt++) a_c[rt] = *(const bf8_t*)(abase + rt*8192);
  #pragma unroll
  for (int it=0; it<4; it++) GLD16(bsrc + 16384 + it*4096 + t*8, &Bs[1][0] + it*4096 + wvb*8);
  #pragma unroll
  for (int rt=0; rt<4; rt++) a_n[rt] = *(const bf8_t*)(abase + rt*8192 + 32);
  for (int ks=0; ks<16; ks++){
    int ksn = ks+2 < 16 ? ks+2 : 15;
    const unsigned short* sb = bsrc + (size_t)ksn*16384;
    unsigned short* db = &Bs[(ks+2)&3][0];
    #pragma unroll
    for (int it=0; it<4; it++) GLD16(sb + it*4096 + t*8, db + it*4096 + wvb*8);
    bf8_t a_nn[4];
    #pragma unroll
    for (int rt=0; rt<4; rt++) a_nn[rt] = *(const bf8_t*)(abase + rt*8192 + ksn*32);
    asm volatile("s_waitcnt vmcnt(16)" ::: "memory");
    __builtin_amdgcn_sched_barrier(0);
    __builtin_amdgcn_s_barrier();
    __builtin_amdgcn_sched_barrier(0);
    const unsigned short* bb = &Bs[ks&3][0] + g*4096 + (colg*128 + li)*8;
    __builtin_amdgcn_s_setprio(1);
    #pragma unroll
    for (int ct=0; ct<8; ct++){
      bf8_t b = *(const bf8_t*)(bb + ct*128);
      #pragma unroll
      for (int rt=0; rt<4; rt++) acc[rt][ct] = mfma16(a_c[rt], b, acc[rt][ct]);
    }
    __builtin_amdgcn_s_setprio(0);
    #pragma unroll
    for (int rt=0; rt<4; rt++){ a_c[rt]=a_n[rt]; a_n[rt]=a_nn[rt]; }
  }
  rf_ln_store4(acc, phi + (size_t)m*NTOT*1024, rowp, rowg, n0, colg, l);
}

// ---------- K3: emb = phi2 @ W2f + b2 -> bf16 ----------
// 128 rows x 256 cols; wave tile 64 rows x 64 cols (RT=4, CT=4); 64KB ring
__global__ __launch_bounds__(512,2) void k_emb(const unsigned short* __restrict__ phi,
    const unsigned short* __restrict__ W2f, const float* __restrict__ b2,
    unsigned short* __restrict__ emb){
  const int m = blockIdx.y, n0 = blockIdx.x*128;
  const int t = threadIdx.x, w = t>>6, l = t&63;
  const int g = l>>4, li = l&15;
  const int rowg = w & 1, colg = w >> 1;
  const int wvb = t & ~63;
  __shared__ unsigned short Bs[4][8192];   // 4 x 16KB ring
  f32x4 acc[4][4];
  const f32x4 z4 = {0.f,0.f,0.f,0.f};
  #pragma unroll
  for (int rt=0;rt<4;rt++)
    #pragma unroll
    for (int ct=0;ct<4;ct++) acc[rt][ct] = z4;
  const unsigned short* abase = phi + ((size_t)m*NTOT + n0 + rowg*64 + li)*1024 + g*8;
  bf8_t a_c[4], a_n[4];
  #pragma unroll
  for (int it=0; it<2; it++) GLD16(W2f + it*4096 + t*8, &Bs[0][0] + it*4096 + wvb*8);
  #pragma unroll
  for (int rt=0; rt<4; rt++) a_c[rt] = *(const bf8_t*)(abase + rt*16384);
  #pragma unroll
  for (int it=0; it<2; it++) GLD16(W2f + 8192 + it*4096 + t*8, &Bs[1][0] + it*4096 + wvb*8);
  #pragma unroll
  for (int rt=0; rt<4; rt++) a_n[rt] = *(const bf8_t*)(abase + rt*16384 + 32);
  for (int ks=0; ks<32; ks++){
    int ksn = ks+2 < 32 ? ks+2 : 31;
    const unsigned short* sb = W2f + (size_t)ksn*8192;
    unsigned short* db = &Bs[(ks+2)&3][0];
    #pragma unroll
    for (int it=0; it<2; it++) GLD16(sb + it*4096 + t*8, db + it*4096 + wvb*8);
    bf8_t a_nn[4];
    #pragma unroll
    for (int rt=0; rt<4; rt++) a_nn[rt] = *(const bf8_t*)(abase + rt*16384 + ksn*32);
    asm volatile("s_waitcnt vmcnt(12)" ::: "memory");
    __builtin_amdgcn_sched_barrier(0);
    __builtin_amdgcn_s_barrier();
    __builtin_amdgcn_sched_barrier(0);
    const unsigned short* bb = &Bs[ks&3][0] + g*2048 + (colg*64 + li)*8;
    __builtin_amdgcn_s_setprio(1);
    #pragma unroll
    for (int ct=0; ct<4; ct++){
      bf8_t b = *(const bf8_t*)(bb + ct*128);
      #pragma unroll
      for (int rt=0; rt<4; rt++) acc[rt][ct] = mfma16(a_c[rt], b, acc[rt][ct]);
    }
    __builtin_amdgcn_s_setprio(0);
    #pragma unroll
    for (int rt=0; rt<4; rt++){ a_c[rt]=a_n[rt]; a_n[rt]=a_nn[rt]; }
  }
  #pragma unroll
  for (int rt=0; rt<4; rt++){
    #pragma unroll
    for (int ct=0; ct<4; ct++){
      int c = colg*64 + ct*16 + li;
      float bv = b2[c];
      #pragma unroll
      for (int j=0;j<4;j++)
        emb[((size_t)m*NTOT + n0 + rowg*64 + rt*16 + 4*g + j)*256 + c] = f2bf(acc[rt][ct][j] + bv);
    }
  }
}

// ---------- K4: scores -> p = exp((emb.Ws + bs)/16) ----------
__global__ __launch_bounds__(256) void k_scores(const unsigned short* __restrict__ emb,
    const float* __restrict__ Wsm, const float* __restrict__ bsv, float* __restrict__ p){
  const int m = blockIdx.y;
  const int n = blockIdx.x*256 + threadIdx.x;
  __shared__ float Wss[1024];
  ((float4*)Wss)[threadIdx.x] = ((const float4*)Wsm)[threadIdx.x];
  __syncthreads();
  const u16x8* er = (const u16x8*)(emb + ((size_t)m*NTOT + n)*256);
  float a0=0.f,a1=0.f,a2=0.f,a3=0.f;
  for (int d8=0; d8<32; d8++){
    u16x8 e = er[d8];
    #pragma unroll
    for (int i=0;i<8;i++){
      float ev = bf2f(e[i]);
      const float* wv = &Wss[(d8*8+i)*4];
      a0 += ev*wv[0]; a1 += ev*wv[1]; a2 += ev*wv[2]; a3 += ev*wv[3];
    }
  }
  float4 o;
  o.x = expf((a0 + bsv[0]) * 0.0625f);
  o.y = expf((a1 + bsv[1]) * 0.0625f);
  o.z = expf((a2 + bsv[2]) * 0.0625f);
  o.w = expf((a3 + bsv[3]) * 0.0625f);
  ((float4*)p)[(size_t)m*NTOT + n] = o;
}

// ---------- K5: bag start offsets ----------
__global__ void k_starts(const int* __restrict__ idx, int* __restrict__ starts){
  int t = threadIdx.x;
  if (t <= NBAG){
    int lo = 0, hi = NTOT;
    while (lo < hi){ int mid = (lo + hi) >> 1; if (idx[mid] < t) lo = mid + 1; else hi = mid; }
    starts[t] = lo;
  }
}

// ---------- K6: en = relu(emb @ Wmf + bm) -> bf16 ----------
__global__ __launch_bounds__(256) void k_embnew(const unsigned short* __restrict__ emb,
    const unsigned short* __restrict__ Wmf, const float* __restrict__ bm,
    unsigned short* __restrict__ en){
  const int m = blockIdx.y, n0 = blockIdx.x*64;
  const int t = threadIdx.x, w = t>>6, l = t&63;
  const int g = l>>4, li = l&15;
  const int wvb = (t & ~63);
  __shared__ unsigned short Bs[32768];   // full Wmf [32][128][8] = 64KB
  #pragma unroll
  for (int it=0; it<16; it++)
    GLD16(Wmf + it*2048 + t*8, Bs + it*2048 + wvb*8);
  asm volatile("s_waitcnt vmcnt(0)" ::: "memory");
  __syncthreads();
  f32x4 acc[8];
  const f32x4 z4 = {0.f,0.f,0.f,0.f};
  #pragma unroll
  for (int ct=0;ct<8;ct++) acc[ct] = z4;
  const unsigned short* arow = emb + ((size_t)m*NTOT + n0 + w*16 + li)*256 + g*8;
  #pragma unroll
  for (int ks=0; ks<8; ks++){
    bf8_t a = *(const bf8_t*)(arow + ks*32);
    #pragma unroll
    for (int ct=0; ct<8; ct++){
      bf8_t b = *(const bf8_t*)(Bs + (ks*4+g)*1024 + (ct*16 + li)*8);
      acc[ct] = mfma16(a, b, acc[ct]);
    }
  }
  #pragma unroll
  for (int ct=0; ct<8; ct++){
    int c = ct*16 + li;
    float bv = bm[c];
    #pragma unroll
    for (int j=0;j<4;j++)
      en[((size_t)m*NTOT + n0 + w*16 + 4*g + j)*128 + c] = f2bf(fmaxf(acc[ct][j] + bv, 0.f));
  }
}

// ---------- K7: per (bag,m): seg = sum p; out[e] = sum_n en * p[k]/seg[k] ----------
__global__ __launch_bounds__(256) void k_pool(const unsigned short* __restrict__ en,
    const float* __restrict__ p, const int* __restrict__ starts, float* __restrict__ out){
  const int b = blockIdx.x, m = blockIdx.y;
  const int t = threadIdx.x;
  const int s0 = starts[b], s1 = starts[b+1];
  float sp0=0.f,sp1=0.f,sp2=0.f,sp3=0.f;
  for (int n = s0 + t; n < s1; n += 256){
    float4 pv = ((const float4*)p)[(size_t)m*NTOT + n];
    sp0 += pv.x; sp1 += pv.y; sp2 += pv.z; sp3 += pv.w;
  }
  #pragma unroll
  for (int off=1; off<64; off<<=1){
    sp0 += __shfl_xor(sp0, off); sp1 += __shfl_xor(sp1, off);
    sp2 += __shfl_xor(sp2, off); sp3 += __shfl_xor(sp3, off);
  }
  __shared__ float wred[4][4];
  __shared__ float winv[4];
  if ((t & 63) == 0){ wred[t>>6][0]=sp0; wred[t>>6][1]=sp1; wred[t>>6][2]=sp2; wred[t>>6][3]=sp3; }
  __syncthreads();
  if (t < 4){
    float s = wred[0][t] + wred[1][t] + wred[2][t] + wred[3][t];
    winv[t] = (s > 0.f) ? 1.0f / s : 0.f;
  }
  __syncthreads();
  const int e = t & 127, half = t >> 7;
  const int k = e >> 5;
  float accv = 0.f;
  for (int n = s0 + half; n < s1; n += 2){
    float wq = p[((size_t)m*NTOT + n)*4 + k];
    float v = bf2f(en[((size_t)m*NTOT + n)*128 + e]);
    accv = fmaf(v, wq, accv);
  }
  accv *= winv[k];
  __shared__ float ac2[2][128];
  ac2[half][e] = accv;
  __syncthreads();
  if (t < 128) out[((size_t)b*NMC + m)*128 + t] = ac2[0][t] + ac2[1][t];
}

extern "C" void kernel_launch(void* const* d_in, const int* in_sizes, int n_in,
                              void* d_out, int out_size, void* d_ws, size_t ws_size,
                              hipStream_t stream) {
  const float* X    = (const float*)d_in[0];
  const int*   Xidx = (const int*)  d_in[1];
  const float* Om1  = (const float*)d_in[2];
  const float* Om2  = (const float*)d_in[3];
  const float* W1   = (const float*)d_in[4];
  const float* b1   = (const float*)d_in[5];
  const float* W2   = (const float*)d_in[6];
  const float* b2   = (const float*)d_in[7];
  const float* Wsm  = (const float*)d_in[8];
  const float* bsv  = (const float*)d_in[9];
  const float* Wm   = (const float*)d_in[10];
  const float* bm   = (const float*)d_in[11];
  float* out = (float*)d_out;

  // ws aliasing (lifetimes are strictly sequential):
  //   [0,128M)    phi  [alive k_phi1..k_emb]; then en/p/starts overlay it
  //   [128M,192M) h    [k_phi2a..k_phi2b]; Xb (before) and emb (after) overlay it
  //   [192M,..)   packed weights (alive whole run)
  char* ws = (char*)d_ws;
  unsigned short* phi  = (unsigned short*)(ws);                    // 128MiB
  unsigned short* en   = (unsigned short*)(ws);                    // 16MiB (alias phi)
  float* p             = (float*)(ws + 16777216ull);               // 1MiB  (alias phi)
  int* starts          = (int*)(ws + 17825792ull);                 // 260B  (alias phi)
  unsigned short* h    = (unsigned short*)(ws + 134217728ull);     // 64MiB
  unsigned short* Xb   = (unsigned short*)(ws + 134217728ull);     // 32MiB (alias h)
  unsigned short* emb  = (unsigned short*)(ws + 134217728ull);     // 32MiB (alias h)
  unsigned short* Om1f = (unsigned short*)(ws + 201326592ull);     // 4MiB
  unsigned short* W1f  = (unsigned short*)(ws + 205520896ull);     // 1MiB
  unsigned short* Om2f = (unsigned short*)(ws + 206569472ull);     // 2MiB
  unsigned short* W2f  = (unsigned short*)(ws + 208666624ull);     // 0.5MiB
  unsigned short* Wmf  = (unsigned short*)(ws + 209190912ull);     // 64KiB

  k_cvt   <<<2048, 256, 0, stream>>>(X, Xb, NTOT*1024/8);
  k_pack8 <<<dim3(256,4), 256, 0, stream>>>(Om1, Om1f, 1024, 512);
  k_pack8 <<<dim3(256,1), 256, 0, stream>>>(W1,  W1f,  1024, 512);
  k_pack8 <<<dim3(128,4), 256, 0, stream>>>(Om2, Om2f, 512,  512);
  k_pack8 <<<dim3(128,1), 256, 0, stream>>>(W2,  W2f,  1024, 256);
  k_pack8 <<<dim3(16,1),  256, 0, stream>>>(Wm,  Wmf,  256,  128);
  k_phi1  <<<dim3(128,4), 512, 0, stream>>>(Xb, Om1f, phi);
  k_phi2a <<<dim3(128,4), 512, 0, stream>>>(phi, W1f, b1, h);
  k_phi2b <<<dim3(128,4), 512, 0, stream>>>(h, Om2f, phi);
  k_emb   <<<dim3(128,4), 512, 0, stream>>>(phi, W2f, b2, emb);
  k_scores<<<dim3(64,4),  256, 0, stream>>>(emb, Wsm, bsv, p);
  k_embnew<<<dim3(256,4), 256, 0, stream>>>(emb, Wmf, bm, en);
  k_starts<<<1, 128, 0, stream>>>(Xidx, starts);
  k_pool  <<<dim3(64,4),  256, 0, stream>>>(en, p, starts, out);
}